// Round 18
// baseline (295.623 us; speedup 1.0000x reference)
//
#include <hip/hip_runtime.h>
#include <hip/hip_bf16.h>

typedef __attribute__((ext_vector_type(8))) short short8;
typedef __attribute__((ext_vector_type(4))) float f32x4;

__device__ __forceinline__ ushort f2b(float f) {
    union { float f; uint u; } v; v.f = f;
    uint u = v.u;
    u += 0x7fffu + ((u >> 16) & 1u);   // RNE
    return (ushort)(u >> 16);
}
__device__ __forceinline__ float blo(uint u) { return __uint_as_float(u << 16); }
__device__ __forceinline__ float bhi(uint u) { return __uint_as_float(u & 0xffff0000u); }

// async global->LDS, 16B per lane; LDS dest = wave-uniform base + lane*16
__device__ __forceinline__ void gl_lds16(const void* g, void* s) {
    __builtin_amdgcn_global_load_lds(
        (const __attribute__((address_space(1))) void*)g,
        (__attribute__((address_space(3))) void*)s, 16, 0, 0);
}

#define ECAP 32768   // ebuf slots per bucket (expected ~16.3K)
#define CCAP 40960   // csr slots per bucket (ECAP + 8K pad)

// ================= fused setup + bucket-scatter (+ global degree histogram) =============

__global__ __launch_bounds__(256) void k_setup_scatter(
    const float* __restrict__ W1, ushort* __restrict__ wt1b, int D,
    const float* __restrict__ W2, ushort* __restrict__ wt2b, int H,
    const int* __restrict__ batch, int N, int G, int* __restrict__ gstart,
    float* __restrict__ psum, float* __restrict__ dinv,
    uint* __restrict__ hb0zrow, uint* __restrict__ hb1zrow,
    const int* __restrict__ ei, int E, int NB, int* __restrict__ bcur,
    int* __restrict__ cnt, uint* __restrict__ ebuf, int c1b, int c2b, int bb) {
    __shared__ int h[128], gb[128], lc[128];
    int b = blockIdx.x, t = threadIdx.x;
    if (b < c1b) {
        int o = b * 256 + t;
        if (o < 128 * D) {
            int n = o / D, k = o - n * D;
            wt1b[o] = f2b(W1[(size_t)k * 128 + n]);
        }
    } else if (b < c1b + c2b) {
        int o = (b - c1b) * 256 + t;
        if (o < 128 * H) {
            int n = o / H, k = o - n * H;
            wt2b[o] = f2b(W2[(size_t)k * 128 + n]);
        }
    } else if (b < c1b + c2b + bb) {
        int i = (b - c1b - c2b) * 256 + t;
        if (i < N) {
            int bt = batch[i];
            int prev = (i == 0) ? -1 : batch[i - 1];
            for (int g = prev + 1; g <= bt; ++g) gstart[g] = i;
            if (i == N - 1)
                for (int g = bt + 1; g <= G; ++g) gstart[g] = N;
        }
    } else if (b == c1b + c2b + bb) {
        for (int i = t; i < G * H; i += 256) psum[i] = 0.f;
        if (t == 0) dinv[N] = 0.f;
        for (int i = t; i < 64; i += 256) { hb0zrow[i] = 0u; hb1zrow[i] = 0u; }
    } else {
        // ---- scatter role: bucket scatter + global degree histogram ----
        int sb = b - (c1b + c2b + bb + 1);
        if (t < 128) { h[t] = 0; lc[t] = 0; }
        __syncthreads();
        int e0 = sb * 2048;
        int r[8], c[8], bk[8];
#pragma unroll
        for (int u = 0; u < 8; ++u) {
            int e = e0 + u * 256 + t;
            if (e < E) {
                r[u] = ei[e];
                c[u] = ei[E + e];
                bk[u] = c[u] >> 10;
                atomicAdd(&h[bk[u]], 1);
                atomicAdd(&cnt[c[u]], 1);     // per-node degree (for GEMM epilogue)
            }
        }
        __syncthreads();
        if (t < NB && h[t]) gb[t] = atomicAdd(&bcur[t], h[t]);
        __syncthreads();
#pragma unroll
        for (int u = 0; u < 8; ++u) {
            int e = e0 + u * 256 + t;
            if (e < E) {
                int p = gb[bk[u]] + atomicAdd(&lc[bk[u]], 1);
                ebuf[(size_t)bk[u] * ECAP + p] = ((uint)(c[u] & 1023) << 22) | (uint)r[u];
            }
        }
    }
}

// ================= fused GEMM1 + bucket sort =================
// Blocks [0, gblocks): MFMA GEMM (A fp32 via gl_lds, BM=128, BK=64, 4 waves x 32 rows),
//   epilogue scale = rsqrtf(cnt[row]+1) (== dinv, available from setup).
// Blocks [gblocks, gblocks+NB): LDS counting sort -> padded csr, offs, dinv.
// Sort (~10us) hides under GEMM (~115us).

template <int NT>
__global__ __launch_bounds__(256) void k_gemm_sort(
    const float* __restrict__ Ap, const ushort* __restrict__ Wt,
    const int* __restrict__ cnt, ushort* __restrict__ outb, int N, int gblocks,
    const uint* __restrict__ ebuf, const int* __restrict__ bcur, int NB,
    uint* __restrict__ offs, float* __restrict__ dinv, int* __restrict__ csr) {
    constexpr int K = NT * 64;
    __shared__ __align__(16) char smem[128 * 64 * 4 + 128 * 64 * 2];
    const int tid = threadIdx.x;

    if ((int)blockIdx.x >= gblocks) {
        // ---------- bucket sort role ----------
        int* cnt_s = (int*)smem;
        int* cur_s = (int*)(smem + 4096);
        int* wsum  = (int*)(smem + 8192);
        int t = tid;
        int b = blockIdx.x - gblocks;
        int node0 = b << 10;
        int nn = min(1024, N - node0);
        for (int i = t; i < nn; i += 256) cnt_s[i] = 0;
        __syncthreads();
        int e0 = b * ECAP, e1 = e0 + bcur[b];
        int e0p = b * CCAP;
        for (int e = e0 + t; e < e1; e += 256) atomicAdd(&cnt_s[ebuf[e] >> 22], 1);
        __syncthreads();
        int i0 = t * 4;
        int x[4], px[4];
#pragma unroll
        for (int j = 0; j < 4; ++j) {
            x[j] = (i0 + j < nn) ? cnt_s[i0 + j] : 0;
            px[j] = (x[j] + 7) & ~7;
        }
        int tot = px[0] + px[1] + px[2] + px[3];
        int run = tot;
        int lane = t & 63, w = t >> 6;
#pragma unroll
        for (int off = 1; off < 64; off <<= 1) {
            int v = __shfl_up(run, off);
            if (lane >= off) run += v;
        }
        if (lane == 63) wsum[w] = run;
        __syncthreads();
        int base = 0;
        for (int u = 0; u < w; ++u) base += wsum[u];
        base += run - tot;
#pragma unroll
        for (int j = 0; j < 4; ++j) {
            if (i0 + j < nn) {
                int node = node0 + i0 + j;
                offs[node] = ((uint)(e0p + base) << 10) | (uint)x[j];
                cur_s[i0 + j] = base;
                dinv[node] = rsqrtf((float)(x[j] + 1));
                for (int k = x[j]; k < px[j]; ++k) csr[e0p + base + k] = N;  // pad
                base += px[j];
            }
        }
        __syncthreads();
        for (int e = e0 + t; e < e1; e += 256) {
            uint v = ebuf[e];
            int p = atomicAdd(&cur_s[v >> 22], 1);
            csr[e0p + p] = (int)(v & 0x3FFFFFu);
        }
        return;
    }

    // ---------- GEMM role ----------
    char* asb = smem;
    char* bsb = smem + 128 * 64 * 4;
    const int row0 = blockIdx.x * 128;
    const int w = tid >> 6, l = tid & 63;
    const int lr = l & 15, lk = l >> 4;
    f32x4 acc[2][8] = {};

    for (int t = 0; t < NT; ++t) {
        const int kb = t * 64;
        const char* A = (const char*)Ap;
#pragma unroll
        for (int i = 0; i < 8; ++i) {
            int b = (w << 13) + (i << 10) + (l << 4);
            int r = b >> 8, cb = b & 255;
            int sb = cb ^ ((r & 15) << 4);
            int gr = row0 + r;
            if (gr < N)
                gl_lds16(A + ((size_t)gr * K + kb) * 4 + sb,
                         asb + (w << 13) + (i << 10));
        }
#pragma unroll
        for (int i = 0; i < 4; ++i) {
            int b = (w << 12) + (i << 10) + (l << 4);
            int r = b >> 7, cb = b & 127;
            int sb = cb ^ ((r & 7) << 4);
            gl_lds16((const char*)Wt + ((size_t)r * K + kb) * 2 + sb,
                     bsb + (w << 12) + (i << 10));
        }
        __syncthreads();
        const int wr0 = w * 32;
#pragma unroll
        for (int ks = 0; ks < 2; ++ks) {
            short8 a0, a1;
            const int r0 = wr0 + lr, r1 = wr0 + 16 + lr;
            const int c0 = ks * 128 + lk * 32;
            float4 v00 = *(const float4*)(asb + (r0 << 8) + ((c0) ^ ((r0 & 15) << 4)));
            float4 v01 = *(const float4*)(asb + (r0 << 8) + ((c0 + 16) ^ ((r0 & 15) << 4)));
            float4 v10 = *(const float4*)(asb + (r1 << 8) + ((c0) ^ ((r1 & 15) << 4)));
            float4 v11 = *(const float4*)(asb + (r1 << 8) + ((c0 + 16) ^ ((r1 & 15) << 4)));
            a0[0] = (short)f2b(v00.x); a0[1] = (short)f2b(v00.y);
            a0[2] = (short)f2b(v00.z); a0[3] = (short)f2b(v00.w);
            a0[4] = (short)f2b(v01.x); a0[5] = (short)f2b(v01.y);
            a0[6] = (short)f2b(v01.z); a0[7] = (short)f2b(v01.w);
            a1[0] = (short)f2b(v10.x); a1[1] = (short)f2b(v10.y);
            a1[2] = (short)f2b(v10.z); a1[3] = (short)f2b(v10.w);
            a1[4] = (short)f2b(v11.x); a1[5] = (short)f2b(v11.y);
            a1[6] = (short)f2b(v11.z); a1[7] = (short)f2b(v11.w);
            const int c0b = ks * 64 + lk * 16;
#pragma unroll
            for (int nf = 0; nf < 8; ++nf) {
                const int nr = nf * 16 + lr;
                short8 bf = *(const short8*)(bsb + (nr << 7) + (c0b ^ ((nr & 7) << 4)));
                acc[0][nf] = __builtin_amdgcn_mfma_f32_16x16x32_bf16(a0, bf, acc[0][nf], 0, 0, 0);
                acc[1][nf] = __builtin_amdgcn_mfma_f32_16x16x32_bf16(a1, bf, acc[1][nf], 0, 0, 0);
            }
        }
        __syncthreads();
    }
#pragma unroll
    for (int mf = 0; mf < 2; ++mf) {
#pragma unroll
        for (int r = 0; r < 4; ++r) {
            int row = row0 + w * 32 + mf * 16 + lk * 4 + r;
            if (row < N) {
                float dv = rsqrtf((float)(cnt[row] + 1));   // == dinv[row]
#pragma unroll
                for (int nf = 0; nf < 8; ++nf)
                    outb[(size_t)row * 128 + nf * 16 + lr] = f2b(acc[mf][nf][r] * dv);
            }
        }
    }
}

// ================= gather helpers =================

#define ACC8(v) { a[0] += blo(v.x); a[1] += bhi(v.x); a[2] += blo(v.y); a[3] += bhi(v.y); \
                  a[4] += blo(v.z); a[5] += bhi(v.z); a[6] += blo(v.w); a[7] += bhi(v.w); }

// ================= SpMM1 fused with GEMM2 =================

__global__ __launch_bounds__(256) void k_spmm_fuse(
    const uint4* __restrict__ hs4, const int* __restrict__ csr,
    const uint* __restrict__ offs, const float* __restrict__ dinv,
    const float* __restrict__ bias, const ushort* __restrict__ W2t,
    ushort* __restrict__ outb, int N) {
    __shared__ __align__(16) char hsb[16 * 256];     // 16 x 128 bf16
    __shared__ __align__(16) char wsb[128 * 256];    // 128 x 128 bf16
    const int tid = threadIdx.x;
    const int grp = tid >> 4, ql = tid & 15;
    const int node = blockIdx.x * 16 + grp;
    const bool active = node < N;
    // ---- stage W2t (32KB, L2-hot), swizzle granule ^= (row & 15) ----
#pragma unroll
    for (int u = 0; u < 8; ++u) {
        int f = u * 256 + tid;
        int row = f >> 4, g = f & 15;
        *(uint4*)(wsb + row * 256 + ((g ^ (row & 15)) << 4)) =
            *(const uint4*)(W2t + (size_t)f * 8);
    }
    // ---- phase 1: gather-sum ----
    float a[8] = {};
    int beg = 0, pend = 0;
    if (active) {
        uint pv = offs[node];
        beg = (int)(pv >> 10);
        pend = beg + (((int)(pv & 1023u) + 7) & ~7);
        uint4 s = hs4[(size_t)node * 16 + ql];   // self loop
        ACC8(s)
    }
    int i = beg;
    for (; i + 16 <= pend; i += 16) {
        int4 s0 = *(const int4*)(csr + i);
        int4 s1 = *(const int4*)(csr + i + 4);
        int4 s2 = *(const int4*)(csr + i + 8);
        int4 s3 = *(const int4*)(csr + i + 12);
        uint4 v0 = hs4[(size_t)s0.x * 16 + ql];
        uint4 v1 = hs4[(size_t)s0.y * 16 + ql];
        uint4 v2 = hs4[(size_t)s0.z * 16 + ql];
        uint4 v3 = hs4[(size_t)s0.w * 16 + ql];
        uint4 v4 = hs4[(size_t)s1.x * 16 + ql];
        uint4 v5 = hs4[(size_t)s1.y * 16 + ql];
        uint4 v6 = hs4[(size_t)s1.z * 16 + ql];
        uint4 v7 = hs4[(size_t)s1.w * 16 + ql];
        uint4 v8 = hs4[(size_t)s2.x * 16 + ql];
        uint4 v9 = hs4[(size_t)s2.y * 16 + ql];
        uint4 va = hs4[(size_t)s2.z * 16 + ql];
        uint4 vb = hs4[(size_t)s2.w * 16 + ql];
        uint4 vc = hs4[(size_t)s3.x * 16 + ql];
        uint4 vd = hs4[(size_t)s3.y * 16 + ql];
        uint4 ve = hs4[(size_t)s3.z * 16 + ql];
        uint4 vf = hs4[(size_t)s3.w * 16 + ql];
        ACC8(v0) ACC8(v1) ACC8(v2) ACC8(v3) ACC8(v4) ACC8(v5) ACC8(v6) ACC8(v7)
        ACC8(v8) ACC8(v9) ACC8(va) ACC8(vb) ACC8(vc) ACC8(vd) ACC8(ve) ACC8(vf)
    }
    if (i < pend) {
        int4 s0 = *(const int4*)(csr + i);
        int4 s1 = *(const int4*)(csr + i + 4);
        uint4 v0 = hs4[(size_t)s0.x * 16 + ql];
        uint4 v1 = hs4[(size_t)s0.y * 16 + ql];
        uint4 v2 = hs4[(size_t)s0.z * 16 + ql];
        uint4 v3 = hs4[(size_t)s0.w * 16 + ql];
        uint4 v4 = hs4[(size_t)s1.x * 16 + ql];
        uint4 v5 = hs4[(size_t)s1.y * 16 + ql];
        uint4 v6 = hs4[(size_t)s1.z * 16 + ql];
        uint4 v7 = hs4[(size_t)s1.w * 16 + ql];
        ACC8(v0) ACC8(v1) ACC8(v2) ACC8(v3) ACC8(v4) ACC8(v5) ACC8(v6) ACC8(v7)
    }
    // ---- h1 = relu(a*dinv + b1) -> swizzled LDS tile ----
    uint4 hv = make_uint4(0u, 0u, 0u, 0u);
    if (active) {
        float dv = dinv[node];
        float4 b0 = ((const float4*)bias)[ql * 2];
        float4 b1v = ((const float4*)bias)[ql * 2 + 1];
        float o0 = fmaxf(fmaf(a[0], dv, b0.x), 0.f);
        float o1 = fmaxf(fmaf(a[1], dv, b0.y), 0.f);
        float o2 = fmaxf(fmaf(a[2], dv, b0.z), 0.f);
        float o3 = fmaxf(fmaf(a[3], dv, b0.w), 0.f);
        float o4 = fmaxf(fmaf(a[4], dv, b1v.x), 0.f);
        float o5 = fmaxf(fmaf(a[5], dv, b1v.y), 0.f);
        float o6 = fmaxf(fmaf(a[6], dv, b1v.z), 0.f);
        float o7 = fmaxf(fmaf(a[7], dv, b1v.w), 0.f);
        hv.x = ((uint)f2b(o1) << 16) | (uint)f2b(o0);
        hv.y = ((uint)f2b(o3) << 16) | (uint)f2b(o2);
        hv.z = ((uint)f2b(o5) << 16) | (uint)f2b(o4);
        hv.w = ((uint)f2b(o7) << 16) | (uint)f2b(o6);
    }
    *(uint4*)(hsb + grp * 256 + ((ql ^ grp) << 4)) = hv;
    __syncthreads();
    // ---- phase 2: 16x128 @ W2t^T, scale by dinv, write ms ----
    const int w = tid >> 6, l = tid & 63;
    const int lr = l & 15, lk = l >> 4;
    f32x4 acc[2] = {};
#pragma unroll
    for (int ks = 0; ks < 4; ++ks) {
        int g0 = ks * 4 + lk;
        short8 af = *(const short8*)(hsb + lr * 256 + ((g0 ^ lr) << 4));
#pragma unroll
        for (int j = 0; j < 2; ++j) {
            int nr = (w * 2 + j) * 16 + lr;
            short8 bf = *(const short8*)(wsb + nr * 256 + ((g0 ^ (nr & 15)) << 4));
            acc[j] = __builtin_amdgcn_mfma_f32_16x16x32_bf16(af, bf, acc[j], 0, 0, 0);
        }
    }
#pragma unroll
    for (int r = 0; r < 4; ++r) {
        int trow = lk * 4 + r;
        int onode = blockIdx.x * 16 + trow;
        if (onode < N) {
            float dv = dinv[onode];
#pragma unroll
            for (int j = 0; j < 2; ++j)
                outb[(size_t)onode * 128 + (w * 2 + j) * 16 + lr] = f2b(acc[j][r] * dv);
        }
    }
}

// ================= SpMM2 + pool: one node per 16-lane group =================

__global__ __launch_bounds__(256) void k_spmm_pool(
    const uint4* __restrict__ hs4, const int* __restrict__ csr,
    const uint* __restrict__ offs, const float* __restrict__ dinv,
    const float* __restrict__ bias,
    float* __restrict__ psum, const int* __restrict__ batch, int N) {
    __shared__ float4 pacc[16][32];
    __shared__ int gid[16];
    const int grp = threadIdx.x >> 4, ql = threadIdx.x & 15;
    const int node = blockIdx.x * 16 + grp;
    const bool active = node < N;
    float a[8] = {};
    int beg = 0, pend = 0;
    if (active) {
        uint pv = offs[node];
        beg = (int)(pv >> 10);
        pend = beg + (((int)(pv & 1023u) + 7) & ~7);
        uint4 s = hs4[(size_t)node * 16 + ql];   // self loop
        ACC8(s)
    }
    int i = beg;
    for (; i + 16 <= pend; i += 16) {
        int4 s0 = *(const int4*)(csr + i);
        int4 s1 = *(const int4*)(csr + i + 4);
        int4 s2 = *(const int4*)(csr + i + 8);
        int4 s3 = *(const int4*)(csr + i + 12);
        uint4 v0 = hs4[(size_t)s0.x * 16 + ql];
        uint4 v1 = hs4[(size_t)s0.y * 16 + ql];
        uint4 v2 = hs4[(size_t)s0.z * 16 + ql];
        uint4 v3 = hs4[(size_t)s0.w * 16 + ql];
        uint4 v4 = hs4[(size_t)s1.x * 16 + ql];
        uint4 v5 = hs4[(size_t)s1.y * 16 + ql];
        uint4 v6 = hs4[(size_t)s1.z * 16 + ql];
        uint4 v7 = hs4[(size_t)s1.w * 16 + ql];
        uint4 v8 = hs4[(size_t)s2.x * 16 + ql];
        uint4 v9 = hs4[(size_t)s2.y * 16 + ql];
        uint4 va = hs4[(size_t)s2.z * 16 + ql];
        uint4 vb = hs4[(size_t)s2.w * 16 + ql];
        uint4 vc = hs4[(size_t)s3.x * 16 + ql];
        uint4 vd = hs4[(size_t)s3.y * 16 + ql];
        uint4 ve = hs4[(size_t)s3.z * 16 + ql];
        uint4 vf = hs4[(size_t)s3.w * 16 + ql];
        ACC8(v0) ACC8(v1) ACC8(v2) ACC8(v3) ACC8(v4) ACC8(v5) ACC8(v6) ACC8(v7)
        ACC8(v8) ACC8(v9) ACC8(va) ACC8(vb) ACC8(vc) ACC8(vd) ACC8(ve) ACC8(vf)
    }
    if (i < pend) {
        int4 s0 = *(const int4*)(csr + i);
        int4 s1 = *(const int4*)(csr + i + 4);
        uint4 v0 = hs4[(size_t)s0.x * 16 + ql];
        uint4 v1 = hs4[(size_t)s0.y * 16 + ql];
        uint4 v2 = hs4[(size_t)s0.z * 16 + ql];
        uint4 v3 = hs4[(size_t)s0.w * 16 + ql];
        uint4 v4 = hs4[(size_t)s1.x * 16 + ql];
        uint4 v5 = hs4[(size_t)s1.y * 16 + ql];
        uint4 v6 = hs4[(size_t)s1.z * 16 + ql];
        uint4 v7 = hs4[(size_t)s1.w * 16 + ql];
        ACC8(v0) ACC8(v1) ACC8(v2) ACC8(v3) ACC8(v4) ACC8(v5) ACC8(v6) ACC8(v7)
    }
    float o[8] = {};
    if (active) {
        float dv = dinv[node];
        float4 b0 = ((const float4*)bias)[ql * 2];
        float4 b1 = ((const float4*)bias)[ql * 2 + 1];
        o[0] = fmaxf(fmaf(a[0], dv, b0.x), 0.f);
        o[1] = fmaxf(fmaf(a[1], dv, b0.y), 0.f);
        o[2] = fmaxf(fmaf(a[2], dv, b0.z), 0.f);
        o[3] = fmaxf(fmaf(a[3], dv, b0.w), 0.f);
        o[4] = fmaxf(fmaf(a[4], dv, b1.x), 0.f);
        o[5] = fmaxf(fmaf(a[5], dv, b1.y), 0.f);
        o[6] = fmaxf(fmaf(a[6], dv, b1.z), 0.f);
        o[7] = fmaxf(fmaf(a[7], dv, b1.w), 0.f);
    }
    pacc[grp][ql * 2]     = make_float4(o[0], o[1], o[2], o[3]);
    pacc[grp][ql * 2 + 1] = make_float4(o[4], o[5], o[6], o[7]);
    if (ql == 0) gid[grp] = active ? batch[node] : -1;
    __syncthreads();
    int t = threadIdx.x;
    if (t < 128) {
        float run = 0.f; int prev = -1;
#pragma unroll
        for (int g2 = 0; g2 < 16; ++g2) {
            int g = gid[g2];
            if (g < 0) continue;
            if (g != prev && prev >= 0) { atomicAdd(&psum[prev * 128 + t], run); run = 0.f; }
            run += ((const float*)pacc[g2])[t];
            prev = g;
        }
        if (prev >= 0) atomicAdd(&psum[prev * 128 + t], run);
    }
}

// ================= final divide =================

__global__ void k_div(const float* __restrict__ psum, const int* __restrict__ gstart,
                      float* __restrict__ out, int total) {
    int i = blockIdx.x * blockDim.x + threadIdx.x;
    if (i < total) {
        int g = i >> 7;
        float c = (float)(gstart[g + 1] - gstart[g]);
        out[i] = psum[i] / fmaxf(c, 1.f);
    }
}

// ================= launch =================

extern "C" void kernel_launch(void* const* d_in, const int* in_sizes, int n_in,
                              void* d_out, int out_size, void* d_ws, size_t ws_size,
                              hipStream_t stream) {
    const float* x     = (const float*)d_in[0];
    const int*   ei    = (const int*)d_in[1];
    const int*   batch = (const int*)d_in[2];
    const float* W1    = (const float*)d_in[3];
    const float* b1    = (const float*)d_in[4];
    const float* W2    = (const float*)d_in[5];
    const float* b2    = (const float*)d_in[6];
    float* outp = (float*)d_out;

    const int N = in_sizes[2];
    const int E = in_sizes[1] / 2;
    const int D = in_sizes[0] / N;   // 512
    const int H = in_sizes[4];       // 128
    const int G = out_size / H;      // 64
    const int NB = (N + 1023) >> 10; // <= 128

    char* ws = (char*)d_ws;
    size_t off = 0;
    auto alloc = [&](size_t bytes) -> char* {
        char* p = ws + off;
        off = (off + bytes + 255) & ~(size_t)255;
        return p;
    };
    float*  dinv    = (float*)alloc((size_t)(N + 1) * 4);
    uint*   offs    = (uint*)alloc((size_t)N * 4);
    int*    gstart  = (int*)alloc((size_t)(G + 1) * 4);
    float*  psum    = (float*)alloc((size_t)G * H * 4);
    int*    bcur    = (int*)alloc(128 * 4);          // contiguous with cnt for one memset
    int*    cnt     = (int*)alloc((size_t)(N + 1) * 4);
    ushort* wt1b    = (ushort*)alloc((size_t)H * D * 2);
    ushort* wt2b    = (ushort*)alloc((size_t)H * H * 2);
    int*    csr     = (int*)alloc((size_t)NB * CCAP * 4);
    uint*   ebuf    = (uint*)alloc((size_t)NB * ECAP * 4);
    char*   hbase   = alloc((size_t)(N + 8) * 2 * H * 2);
    ushort* hb0     = (ushort*)hbase;                              // N rows + zero row
    ushort* hb1     = (ushort*)(hbase + ((size_t)N + 8) * H * 2);  // N rows + zero row
    (void)ws_size; (void)n_in;

    // zero bcur + cnt in one shot (they are adjacent in ws)
    hipMemsetAsync(bcur, 0, (size_t)((char*)(cnt + N + 1) - (char*)bcur), stream);

    int c1b = (128 * D + 255) / 256;
    int c2b = (128 * H + 255) / 256;
    int bb  = (N + 255) / 256;
    int scb = (E + 2047) / 2048;

    k_setup_scatter<<<c1b + c2b + bb + 1 + scb, 256, 0, stream>>>(
        W1, wt1b, D, W2, wt2b, H, batch, N, G, gstart, psum, dinv,
        (uint*)(hb0 + (size_t)N * H), (uint*)(hb1 + (size_t)N * H),
        ei, E, NB, bcur, cnt, ebuf, c1b, c2b, bb);

    int gblocks = (N + 127) / 128;
    int sblocks = (N + 15) / 16;
    // layer 1 GEMM (K=512 -> NT=8) with fused bucket sort: hb0 = (x@W1t^T)*dinv
    k_gemm_sort<8><<<gblocks + NB, 256, 0, stream>>>(
        x, wt1b, cnt, hb0, N, gblocks, ebuf, bcur, NB, offs, dinv, csr);
    // SpMM1 + fused GEMM2: hb1 = dinv*(relu(...) @ W2)
    k_spmm_fuse<<<sblocks, 256, 0, stream>>>(
        (const uint4*)hb0, csr, offs, dinv, b1, wt2b, hb1, N);
    // SpMM2 + pool
    k_spmm_pool<<<sblocks, 256, 0, stream>>>(
        (const uint4*)hb1, csr, offs, dinv, b2, psum, batch, N);
    // finalize mean
    k_div<<<(G * H + 255) / 256, 256, 0, stream>>>(psum, gstart, outp, G * H);
}

// Round 19
// 248.372 us; speedup vs baseline: 1.1902x; 1.1902x over previous
//
#include <hip/hip_runtime.h>
#include <hip/hip_bf16.h>

typedef __attribute__((ext_vector_type(8))) short short8;
typedef __attribute__((ext_vector_type(4))) float f32x4;

__device__ __forceinline__ ushort f2b(float f) {
    union { float f; uint u; } v; v.f = f;
    uint u = v.u;
    u += 0x7fffu + ((u >> 16) & 1u);   // RNE
    return (ushort)(u >> 16);
}
__device__ __forceinline__ float blo(uint u) { return __uint_as_float(u << 16); }
__device__ __forceinline__ float bhi(uint u) { return __uint_as_float(u & 0xffff0000u); }

// async global->LDS, 16B per lane; LDS dest = wave-uniform base + lane*16
__device__ __forceinline__ void gl_lds16(const void* g, void* s) {
    __builtin_amdgcn_global_load_lds(
        (const __attribute__((address_space(1))) void*)g,
        (__attribute__((address_space(3))) void*)s, 16, 0, 0);
}

#define ECAP 32768   // ebuf slots per bucket (expected ~16.3K)
#define CCAP 40960   // csr slots per bucket (ECAP + 8K pad)

// ================= fused setup + bucket-scatter =================

__global__ __launch_bounds__(256) void k_setup_scatter(
    const float* __restrict__ W1, ushort* __restrict__ wt1b, int D,
    const float* __restrict__ W2, ushort* __restrict__ wt2b, int H,
    const int* __restrict__ batch, int N, int G, int* __restrict__ gstart,
    float* __restrict__ psum, float* __restrict__ dinv,
    uint* __restrict__ hb0zrow, uint* __restrict__ hb1zrow,
    const int* __restrict__ ei, int E, int NB, int* __restrict__ bcur,
    uint* __restrict__ ebuf, int c1b, int c2b, int bb) {
    __shared__ int h[128], gb[128], lc[128];
    int b = blockIdx.x, t = threadIdx.x;
    if (b < c1b) {
        int o = b * 256 + t;
        if (o < 128 * D) {
            int n = o / D, k = o - n * D;
            wt1b[o] = f2b(W1[(size_t)k * 128 + n]);
        }
    } else if (b < c1b + c2b) {
        int o = (b - c1b) * 256 + t;
        if (o < 128 * H) {
            int n = o / H, k = o - n * H;
            wt2b[o] = f2b(W2[(size_t)k * 128 + n]);
        }
    } else if (b < c1b + c2b + bb) {
        int i = (b - c1b - c2b) * 256 + t;
        if (i < N) {
            int bt = batch[i];
            int prev = (i == 0) ? -1 : batch[i - 1];
            for (int g = prev + 1; g <= bt; ++g) gstart[g] = i;
            if (i == N - 1)
                for (int g = bt + 1; g <= G; ++g) gstart[g] = N;
        }
    } else if (b == c1b + c2b + bb) {
        for (int i = t; i < G * H; i += 256) psum[i] = 0.f;
        if (t == 0) dinv[N] = 0.f;
        for (int i = t; i < 64; i += 256) { hb0zrow[i] = 0u; hb1zrow[i] = 0u; }
    } else {
        // ---- scatter role ----
        int sb = b - (c1b + c2b + bb + 1);
        if (t < 128) { h[t] = 0; lc[t] = 0; }
        __syncthreads();
        int e0 = sb * 2048;
        int r[8], c[8], bk[8];
#pragma unroll
        for (int u = 0; u < 8; ++u) {
            int e = e0 + u * 256 + t;
            if (e < E) {
                r[u] = ei[e];
                c[u] = ei[E + e];
                bk[u] = c[u] >> 10;
                atomicAdd(&h[bk[u]], 1);
            }
        }
        __syncthreads();
        if (t < NB && h[t]) gb[t] = atomicAdd(&bcur[t], h[t]);
        __syncthreads();
#pragma unroll
        for (int u = 0; u < 8; ++u) {
            int e = e0 + u * 256 + t;
            if (e < E) {
                int p = gb[bk[u]] + atomicAdd(&lc[bk[u]], 1);
                ebuf[(size_t)bk[u] * ECAP + p] = ((uint)(c[u] & 1023) << 22) | (uint)r[u];
            }
        }
    }
}

// ================= bucket sort: LDS counting sort -> padded csr =================

__global__ __launch_bounds__(256) void k_bucket_sort(const uint* __restrict__ ebuf,
                                                     const int* __restrict__ bcur,
                                                     int N, int NB,
                                                     uint* __restrict__ offs,
                                                     float* __restrict__ dinv,
                                                     int* __restrict__ csr) {
    __shared__ int cnt[1024];
    __shared__ int cur[1024];
    __shared__ int wsum[4];
    int t = threadIdx.x;
    int b = blockIdx.x;
    int node0 = b << 10;
    int nn = min(1024, N - node0);
    for (int i = t; i < nn; i += 256) cnt[i] = 0;
    __syncthreads();
    int e0 = b * ECAP, e1 = e0 + bcur[b];
    int e0p = b * CCAP;
    for (int e = e0 + t; e < e1; e += 256) atomicAdd(&cnt[ebuf[e] >> 22], 1);
    __syncthreads();
    int i0 = t * 4;
    int x[4], px[4];
#pragma unroll
    for (int j = 0; j < 4; ++j) {
        x[j] = (i0 + j < nn) ? cnt[i0 + j] : 0;
        px[j] = (x[j] + 7) & ~7;
    }
    int tot = px[0] + px[1] + px[2] + px[3];
    int run = tot;
    int lane = t & 63, w = t >> 6;
#pragma unroll
    for (int off = 1; off < 64; off <<= 1) {
        int v = __shfl_up(run, off);
        if (lane >= off) run += v;
    }
    if (lane == 63) wsum[w] = run;
    __syncthreads();
    int base = 0;
    for (int u = 0; u < w; ++u) base += wsum[u];
    base += run - tot;
#pragma unroll
    for (int j = 0; j < 4; ++j) {
        if (i0 + j < nn) {
            int node = node0 + i0 + j;
            offs[node] = ((uint)(e0p + base) << 10) | (uint)x[j];
            cur[i0 + j] = base;
            dinv[node] = rsqrtf((float)(x[j] + 1));
            for (int k = x[j]; k < px[j]; ++k) csr[e0p + base + k] = N;  // pad
            base += px[j];
        }
    }
    __syncthreads();
    for (int e = e0 + t; e < e1; e += 256) {
        uint v = ebuf[e];
        int p = atomicAdd(&cur[v >> 22], 1);
        csr[e0p + p] = (int)(v & 0x3FFFFFu);
    }
}

// ================= MFMA GEMM (global_load_lds): out = bf16((A@Wt^T) * dinv) =================
// A fp32, staged fp32 in LDS, cvt at frag read. BM=128, BK=64, 4 waves x 32 rows.
// K-loop PHASE-STAGGERED per block (t = (tt + blockIdx) & (NT-1)) so concurrent
// blocks' 256B/row bursts cover all HBM channel subsets, not just t=0's.

template <int NT>
__global__ __launch_bounds__(256) void k_gemm(
    const float* __restrict__ Ap, const ushort* __restrict__ Wt,
    const float* __restrict__ dinv, ushort* __restrict__ outb, int N) {
    constexpr int K = NT * 64;
    __shared__ __align__(16) char asb[128 * 64 * 4];
    __shared__ __align__(16) char bsb[128 * 64 * 2];
    const int tid = threadIdx.x;
    const int row0 = blockIdx.x * 128;
    const int w = tid >> 6, l = tid & 63;
    const int lr = l & 15, lk = l >> 4;
    f32x4 acc[2][8] = {};

    for (int tt = 0; tt < NT; ++tt) {
        const int t = (tt + (int)blockIdx.x) & (NT - 1);   // staggered K phase
        const int kb = t * 64;
        const char* A = (const char*)Ap;
#pragma unroll
        for (int i = 0; i < 8; ++i) {
            int b = (w << 13) + (i << 10) + (l << 4);
            int r = b >> 8, cb = b & 255;
            int sb = cb ^ ((r & 15) << 4);
            int gr = row0 + r;
            if (gr < N)
                gl_lds16(A + ((size_t)gr * K + kb) * 4 + sb,
                         asb + (w << 13) + (i << 10));
        }
#pragma unroll
        for (int i = 0; i < 4; ++i) {
            int b = (w << 12) + (i << 10) + (l << 4);
            int r = b >> 7, cb = b & 127;
            int sb = cb ^ ((r & 7) << 4);
            gl_lds16((const char*)Wt + ((size_t)r * K + kb) * 2 + sb,
                     bsb + (w << 12) + (i << 10));
        }
        __syncthreads();
        const int wr0 = w * 32;
#pragma unroll
        for (int ks = 0; ks < 2; ++ks) {
            short8 a0, a1;
            const int r0 = wr0 + lr, r1 = wr0 + 16 + lr;
            const int c0 = ks * 128 + lk * 32;
            float4 v00 = *(const float4*)(asb + (r0 << 8) + ((c0) ^ ((r0 & 15) << 4)));
            float4 v01 = *(const float4*)(asb + (r0 << 8) + ((c0 + 16) ^ ((r0 & 15) << 4)));
            float4 v10 = *(const float4*)(asb + (r1 << 8) + ((c0) ^ ((r1 & 15) << 4)));
            float4 v11 = *(const float4*)(asb + (r1 << 8) + ((c0 + 16) ^ ((r1 & 15) << 4)));
            a0[0] = (short)f2b(v00.x); a0[1] = (short)f2b(v00.y);
            a0[2] = (short)f2b(v00.z); a0[3] = (short)f2b(v00.w);
            a0[4] = (short)f2b(v01.x); a0[5] = (short)f2b(v01.y);
            a0[6] = (short)f2b(v01.z); a0[7] = (short)f2b(v01.w);
            a1[0] = (short)f2b(v10.x); a1[1] = (short)f2b(v10.y);
            a1[2] = (short)f2b(v10.z); a1[3] = (short)f2b(v10.w);
            a1[4] = (short)f2b(v11.x); a1[5] = (short)f2b(v11.y);
            a1[6] = (short)f2b(v11.z); a1[7] = (short)f2b(v11.w);
            const int c0b = ks * 64 + lk * 16;
#pragma unroll
            for (int nf = 0; nf < 8; ++nf) {
                const int nr = nf * 16 + lr;
                short8 bf = *(const short8*)(bsb + (nr << 7) + (c0b ^ ((nr & 7) << 4)));
                acc[0][nf] = __builtin_amdgcn_mfma_f32_16x16x32_bf16(a0, bf, acc[0][nf], 0, 0, 0);
                acc[1][nf] = __builtin_amdgcn_mfma_f32_16x16x32_bf16(a1, bf, acc[1][nf], 0, 0, 0);
            }
        }
        __syncthreads();
    }
#pragma unroll
    for (int mf = 0; mf < 2; ++mf) {
#pragma unroll
        for (int r = 0; r < 4; ++r) {
            int row = row0 + w * 32 + mf * 16 + lk * 4 + r;
            if (row < N) {
                float dv = dinv[row];
#pragma unroll
                for (int nf = 0; nf < 8; ++nf)
                    outb[(size_t)row * 128 + nf * 16 + lr] = f2b(acc[mf][nf][r] * dv);
            }
        }
    }
}

// ================= gather helpers =================

#define ACC8(v) { a[0] += blo(v.x); a[1] += bhi(v.x); a[2] += blo(v.y); a[3] += bhi(v.y); \
                  a[4] += blo(v.z); a[5] += bhi(v.z); a[6] += blo(v.w); a[7] += bhi(v.w); }

// ================= SpMM1 fused with GEMM2 =================

__global__ __launch_bounds__(256) void k_spmm_fuse(
    const uint4* __restrict__ hs4, const int* __restrict__ csr,
    const uint* __restrict__ offs, const float* __restrict__ dinv,
    const float* __restrict__ bias, const ushort* __restrict__ W2t,
    ushort* __restrict__ outb, int N) {
    __shared__ __align__(16) char hsb[16 * 256];     // 16 x 128 bf16
    __shared__ __align__(16) char wsb[128 * 256];    // 128 x 128 bf16
    const int tid = threadIdx.x;
    const int grp = tid >> 4, ql = tid & 15;
    const int node = blockIdx.x * 16 + grp;
    const bool active = node < N;
    // ---- stage W2t (32KB, L2-hot), swizzle granule ^= (row & 15) ----
#pragma unroll
    for (int u = 0; u < 8; ++u) {
        int f = u * 256 + tid;
        int row = f >> 4, g = f & 15;
        *(uint4*)(wsb + row * 256 + ((g ^ (row & 15)) << 4)) =
            *(const uint4*)(W2t + (size_t)f * 8);
    }
    // ---- phase 1: gather-sum ----
    float a[8] = {};
    int beg = 0, pend = 0;
    if (active) {
        uint pv = offs[node];
        beg = (int)(pv >> 10);
        pend = beg + (((int)(pv & 1023u) + 7) & ~7);
        uint4 s = hs4[(size_t)node * 16 + ql];   // self loop
        ACC8(s)
    }
    int i = beg;
    for (; i + 16 <= pend; i += 16) {
        int4 s0 = *(const int4*)(csr + i);
        int4 s1 = *(const int4*)(csr + i + 4);
        int4 s2 = *(const int4*)(csr + i + 8);
        int4 s3 = *(const int4*)(csr + i + 12);
        uint4 v0 = hs4[(size_t)s0.x * 16 + ql];
        uint4 v1 = hs4[(size_t)s0.y * 16 + ql];
        uint4 v2 = hs4[(size_t)s0.z * 16 + ql];
        uint4 v3 = hs4[(size_t)s0.w * 16 + ql];
        uint4 v4 = hs4[(size_t)s1.x * 16 + ql];
        uint4 v5 = hs4[(size_t)s1.y * 16 + ql];
        uint4 v6 = hs4[(size_t)s1.z * 16 + ql];
        uint4 v7 = hs4[(size_t)s1.w * 16 + ql];
        uint4 v8 = hs4[(size_t)s2.x * 16 + ql];
        uint4 v9 = hs4[(size_t)s2.y * 16 + ql];
        uint4 va = hs4[(size_t)s2.z * 16 + ql];
        uint4 vb = hs4[(size_t)s2.w * 16 + ql];
        uint4 vc = hs4[(size_t)s3.x * 16 + ql];
        uint4 vd = hs4[(size_t)s3.y * 16 + ql];
        uint4 ve = hs4[(size_t)s3.z * 16 + ql];
        uint4 vf = hs4[(size_t)s3.w * 16 + ql];
        ACC8(v0) ACC8(v1) ACC8(v2) ACC8(v3) ACC8(v4) ACC8(v5) ACC8(v6) ACC8(v7)
        ACC8(v8) ACC8(v9) ACC8(va) ACC8(vb) ACC8(vc) ACC8(vd) ACC8(ve) ACC8(vf)
    }
    if (i < pend) {
        int4 s0 = *(const int4*)(csr + i);
        int4 s1 = *(const int4*)(csr + i + 4);
        uint4 v0 = hs4[(size_t)s0.x * 16 + ql];
        uint4 v1 = hs4[(size_t)s0.y * 16 + ql];
        uint4 v2 = hs4[(size_t)s0.z * 16 + ql];
        uint4 v3 = hs4[(size_t)s0.w * 16 + ql];
        uint4 v4 = hs4[(size_t)s1.x * 16 + ql];
        uint4 v5 = hs4[(size_t)s1.y * 16 + ql];
        uint4 v6 = hs4[(size_t)s1.z * 16 + ql];
        uint4 v7 = hs4[(size_t)s1.w * 16 + ql];
        ACC8(v0) ACC8(v1) ACC8(v2) ACC8(v3) ACC8(v4) ACC8(v5) ACC8(v6) ACC8(v7)
    }
    // ---- h1 = relu(a*dinv + b1) -> swizzled LDS tile ----
    uint4 hv = make_uint4(0u, 0u, 0u, 0u);
    if (active) {
        float dv = dinv[node];
        float4 b0 = ((const float4*)bias)[ql * 2];
        float4 b1v = ((const float4*)bias)[ql * 2 + 1];
        float o0 = fmaxf(fmaf(a[0], dv, b0.x), 0.f);
        float o1 = fmaxf(fmaf(a[1], dv, b0.y), 0.f);
        float o2 = fmaxf(fmaf(a[2], dv, b0.z), 0.f);
        float o3 = fmaxf(fmaf(a[3], dv, b0.w), 0.f);
        float o4 = fmaxf(fmaf(a[4], dv, b1v.x), 0.f);
        float o5 = fmaxf(fmaf(a[5], dv, b1v.y), 0.f);
        float o6 = fmaxf(fmaf(a[6], dv, b1v.z), 0.f);
        float o7 = fmaxf(fmaf(a[7], dv, b1v.w), 0.f);
        hv.x = ((uint)f2b(o1) << 16) | (uint)f2b(o0);
        hv.y = ((uint)f2b(o3) << 16) | (uint)f2b(o2);
        hv.z = ((uint)f2b(o5) << 16) | (uint)f2b(o4);
        hv.w = ((uint)f2b(o7) << 16) | (uint)f2b(o6);
    }
    *(uint4*)(hsb + grp * 256 + ((ql ^ grp) << 4)) = hv;
    __syncthreads();
    // ---- phase 2: 16x128 @ W2t^T, scale by dinv, write ms ----
    const int w = tid >> 6, l = tid & 63;
    const int lr = l & 15, lk = l >> 4;
    f32x4 acc[2] = {};
#pragma unroll
    for (int ks = 0; ks < 4; ++ks) {
        int g0 = ks * 4 + lk;
        short8 af = *(const short8*)(hsb + lr * 256 + ((g0 ^ lr) << 4));
#pragma unroll
        for (int j = 0; j < 2; ++j) {
            int nr = (w * 2 + j) * 16 + lr;
            short8 bf = *(const short8*)(wsb + nr * 256 + ((g0 ^ (nr & 15)) << 4));
            acc[j] = __builtin_amdgcn_mfma_f32_16x16x32_bf16(af, bf, acc[j], 0, 0, 0);
        }
    }
#pragma unroll
    for (int r = 0; r < 4; ++r) {
        int trow = lk * 4 + r;
        int onode = blockIdx.x * 16 + trow;
        if (onode < N) {
            float dv = dinv[onode];
#pragma unroll
            for (int j = 0; j < 2; ++j)
                outb[(size_t)onode * 128 + (w * 2 + j) * 16 + lr] = f2b(acc[j][r] * dv);
        }
    }
}

// ================= SpMM2 + pool: one node per 16-lane group =================

__global__ __launch_bounds__(256) void k_spmm_pool(
    const uint4* __restrict__ hs4, const int* __restrict__ csr,
    const uint* __restrict__ offs, const float* __restrict__ dinv,
    const float* __restrict__ bias,
    float* __restrict__ psum, const int* __restrict__ batch, int N) {
    __shared__ float4 pacc[16][32];
    __shared__ int gid[16];
    const int grp = threadIdx.x >> 4, ql = threadIdx.x & 15;
    const int node = blockIdx.x * 16 + grp;
    const bool active = node < N;
    float a[8] = {};
    int beg = 0, pend = 0;
    if (active) {
        uint pv = offs[node];
        beg = (int)(pv >> 10);
        pend = beg + (((int)(pv & 1023u) + 7) & ~7);
        uint4 s = hs4[(size_t)node * 16 + ql];   // self loop
        ACC8(s)
    }
    int i = beg;
    for (; i + 16 <= pend; i += 16) {
        int4 s0 = *(const int4*)(csr + i);
        int4 s1 = *(const int4*)(csr + i + 4);
        int4 s2 = *(const int4*)(csr + i + 8);
        int4 s3 = *(const int4*)(csr + i + 12);
        uint4 v0 = hs4[(size_t)s0.x * 16 + ql];
        uint4 v1 = hs4[(size_t)s0.y * 16 + ql];
        uint4 v2 = hs4[(size_t)s0.z * 16 + ql];
        uint4 v3 = hs4[(size_t)s0.w * 16 + ql];
        uint4 v4 = hs4[(size_t)s1.x * 16 + ql];
        uint4 v5 = hs4[(size_t)s1.y * 16 + ql];
        uint4 v6 = hs4[(size_t)s1.z * 16 + ql];
        uint4 v7 = hs4[(size_t)s1.w * 16 + ql];
        uint4 v8 = hs4[(size_t)s2.x * 16 + ql];
        uint4 v9 = hs4[(size_t)s2.y * 16 + ql];
        uint4 va = hs4[(size_t)s2.z * 16 + ql];
        uint4 vb = hs4[(size_t)s2.w * 16 + ql];
        uint4 vc = hs4[(size_t)s3.x * 16 + ql];
        uint4 vd = hs4[(size_t)s3.y * 16 + ql];
        uint4 ve = hs4[(size_t)s3.z * 16 + ql];
        uint4 vf = hs4[(size_t)s3.w * 16 + ql];
        ACC8(v0) ACC8(v1) ACC8(v2) ACC8(v3) ACC8(v4) ACC8(v5) ACC8(v6) ACC8(v7)
        ACC8(v8) ACC8(v9) ACC8(va) ACC8(vb) ACC8(vc) ACC8(vd) ACC8(ve) ACC8(vf)
    }
    if (i < pend) {
        int4 s0 = *(const int4*)(csr + i);
        int4 s1 = *(const int4*)(csr + i + 4);
        uint4 v0 = hs4[(size_t)s0.x * 16 + ql];
        uint4 v1 = hs4[(size_t)s0.y * 16 + ql];
        uint4 v2 = hs4[(size_t)s0.z * 16 + ql];
        uint4 v3 = hs4[(size_t)s0.w * 16 + ql];
        uint4 v4 = hs4[(size_t)s1.x * 16 + ql];
        uint4 v5 = hs4[(size_t)s1.y * 16 + ql];
        uint4 v6 = hs4[(size_t)s1.z * 16 + ql];
        uint4 v7 = hs4[(size_t)s1.w * 16 + ql];
        ACC8(v0) ACC8(v1) ACC8(v2) ACC8(v3) ACC8(v4) ACC8(v5) ACC8(v6) ACC8(v7)
    }
    float o[8] = {};
    if (active) {
        float dv = dinv[node];
        float4 b0 = ((const float4*)bias)[ql * 2];
        float4 b1 = ((const float4*)bias)[ql * 2 + 1];
        o[0] = fmaxf(fmaf(a[0], dv, b0.x), 0.f);
        o[1] = fmaxf(fmaf(a[1], dv, b0.y), 0.f);
        o[2] = fmaxf(fmaf(a[2], dv, b0.z), 0.f);
        o[3] = fmaxf(fmaf(a[3], dv, b0.w), 0.f);
        o[4] = fmaxf(fmaf(a[4], dv, b1.x), 0.f);
        o[5] = fmaxf(fmaf(a[5], dv, b1.y), 0.f);
        o[6] = fmaxf(fmaf(a[6], dv, b1.z), 0.f);
        o[7] = fmaxf(fmaf(a[7], dv, b1.w), 0.f);
    }
    pacc[grp][ql * 2]     = make_float4(o[0], o[1], o[2], o[3]);
    pacc[grp][ql * 2 + 1] = make_float4(o[4], o[5], o[6], o[7]);
    if (ql == 0) gid[grp] = active ? batch[node] : -1;
    __syncthreads();
    int t = threadIdx.x;
    if (t < 128) {
        float run = 0.f; int prev = -1;
#pragma unroll
        for (int g2 = 0; g2 < 16; ++g2) {
            int g = gid[g2];
            if (g < 0) continue;
            if (g != prev && prev >= 0) { atomicAdd(&psum[prev * 128 + t], run); run = 0.f; }
            run += ((const float*)pacc[g2])[t];
            prev = g;
        }
        if (prev >= 0) atomicAdd(&psum[prev * 128 + t], run);
    }
}

// ================= final divide =================

__global__ void k_div(const float* __restrict__ psum, const int* __restrict__ gstart,
                      float* __restrict__ out, int total) {
    int i = blockIdx.x * blockDim.x + threadIdx.x;
    if (i < total) {
        int g = i >> 7;
        float c = (float)(gstart[g + 1] - gstart[g]);
        out[i] = psum[i] / fmaxf(c, 1.f);
    }
}

// ================= launch =================

extern "C" void kernel_launch(void* const* d_in, const int* in_sizes, int n_in,
                              void* d_out, int out_size, void* d_ws, size_t ws_size,
                              hipStream_t stream) {
    const float* x     = (const float*)d_in[0];
    const int*   ei    = (const int*)d_in[1];
    const int*   batch = (const int*)d_in[2];
    const float* W1    = (const float*)d_in[3];
    const float* b1    = (const float*)d_in[4];
    const float* W2    = (const float*)d_in[5];
    const float* b2    = (const float*)d_in[6];
    float* outp = (float*)d_out;

    const int N = in_sizes[2];
    const int E = in_sizes[1] / 2;
    const int D = in_sizes[0] / N;   // 512
    const int H = in_sizes[4];       // 128
    const int G = out_size / H;      // 64
    const int NB = (N + 1023) >> 10; // <= 128

    char* ws = (char*)d_ws;
    size_t off = 0;
    auto alloc = [&](size_t bytes) -> char* {
        char* p = ws + off;
        off = (off + bytes + 255) & ~(size_t)255;
        return p;
    };
    float*  dinv    = (float*)alloc((size_t)(N + 1) * 4);
    uint*   offs    = (uint*)alloc((size_t)N * 4);
    int*    gstart  = (int*)alloc((size_t)(G + 1) * 4);
    float*  psum    = (float*)alloc((size_t)G * H * 4);
    int*    bcur    = (int*)alloc(128 * 4);
    ushort* wt1b    = (ushort*)alloc((size_t)H * D * 2);
    ushort* wt2b    = (ushort*)alloc((size_t)H * H * 2);
    int*    csr     = (int*)alloc((size_t)NB * CCAP * 4);
    uint*   ebuf    = (uint*)alloc((size_t)NB * ECAP * 4);
    char*   hbase   = alloc((size_t)(N + 8) * 2 * H * 2);
    ushort* hb0     = (ushort*)hbase;                              // N rows + zero row
    ushort* hb1     = (ushort*)(hbase + ((size_t)N + 8) * H * 2);  // N rows + zero row
    (void)ws_size; (void)n_in;

    hipMemsetAsync(bcur, 0, 128 * 4, stream);

    int c1b = (128 * D + 255) / 256;
    int c2b = (128 * H + 255) / 256;
    int bb  = (N + 255) / 256;
    int scb = (E + 2047) / 2048;

    k_setup_scatter<<<c1b + c2b + bb + 1 + scb, 256, 0, stream>>>(
        W1, wt1b, D, W2, wt2b, H, batch, N, G, gstart, psum, dinv,
        (uint*)(hb0 + (size_t)N * H), (uint*)(hb1 + (size_t)N * H),
        ei, E, NB, bcur, ebuf, c1b, c2b, bb);

    k_bucket_sort<<<NB, 256, 0, stream>>>(ebuf, bcur, N, NB, offs, dinv, csr);

    int gblocks = (N + 127) / 128;
    int sblocks = (N + 15) / 16;
    // layer 1 GEMM (K=512 -> NT=8, K-phase staggered): hb0 = (x@W1t^T)*dinv
    k_gemm<8><<<gblocks, 256, 0, stream>>>(x, wt1b, dinv, hb0, N);
    // SpMM1 + fused GEMM2: hb1 = dinv*(relu(...) @ W2)
    k_spmm_fuse<<<sblocks, 256, 0, stream>>>(
        (const uint4*)hb0, csr, offs, dinv, b1, wt2b, hb1, N);
    // SpMM2 + pool
    k_spmm_pool<<<sblocks, 256, 0, stream>>>(
        (const uint4*)hb1, csr, offs, dinv, b2, psum, batch, N);
    // finalize mean
    k_div<<<(G * H + 255) / 256, 256, 0, stream>>>(psum, gstart, outp, G * H);
}